// Round 7
// baseline (1255.533 us; speedup 1.0000x reference)
//
#include <hip/hip_runtime.h>
#include <cmath>

typedef __attribute__((ext_vector_type(8))) short short8;
typedef __attribute__((ext_vector_type(4))) float f32x4;
typedef unsigned short u16;

#define NB   16
#define NC   128
#define NS   64
#define NW   64
#define NHH  128
#define GSTR (NHH * NC * 3)

// workspace layout (bytes)
#define WI_OFF 0u            // Wi packed: 512*256*2 = 262144
#define WS_OFF 262144u       // Ws packed: 512*384*2 = 393216
#define FS_OFF 1048576u      // fs (bias included): 1024 * 512*64 * 2 = 67108864
#define WS_NEEDED (FS_OFF + (size_t)NB * NS * 512 * NW * 2)

__device__ __forceinline__ u16 f2bf(float f) {
    unsigned u = __builtin_bit_cast(unsigned, f);
    u += 0x7fffu + ((u >> 16) & 1u);
    return (u16)(u >> 16);
}
__device__ __forceinline__ float bfreg(uint2 u, int r) {
    unsigned w = (r < 2) ? u.x : u.y;
    unsigned bits = (r & 1) ? (w & 0xffff0000u) : (w << 16);
    return __builtin_bit_cast(float, bits);
}
__device__ __forceinline__ float fsig(float x) {
    return __builtin_amdgcn_rcpf(1.f + __builtin_amdgcn_exp2f(x * -1.442695041f));
}
__device__ __forceinline__ float ftanh(float x) {
    return 1.f - 2.f * __builtin_amdgcn_rcpf(1.f + __builtin_amdgcn_exp2f(x * 2.885390082f));
}

// ---------------- phase 0: pack weights into MFMA A-fragment layout (bf16) ----
// Wi layout (consumed by itos_gemm):
//   wip[(((wv*4+g)*8+kt)*64+l)*8+j], m=128g+16wv+(l&15), k=kt*32+(l>>4)*8+j -> (dy,c)
// Ws layout (consumed by rowlstm_w16, keyed by vh=wv):
//   wsp[(((wv*4+g)*12+kt)*64+l)*8+j], m=128g+16wv+(l&15), k -> (d=k>>7, c=k&127)
__global__ void pack_weights(const float* __restrict__ w_itos,
                             const float* __restrict__ w_stos,
                             u16* __restrict__ wip, u16* __restrict__ wsp) {
    int e = blockIdx.x * 256 + threadIdx.x;
    if (e < 131072) {
        int j = e & 7, l = (e >> 3) & 63, kt = (e >> 9) & 7, wvg = e >> 12;
        int wv = wvg >> 2, g = wvg & 3;
        int m = 128 * g + 16 * wv + (l & 15);
        int k = kt * 32 + (l >> 4) * 8 + j;
        int dy = k >> 7, c = k & 127;
        wip[e] = f2bf(w_itos[(m * 128 + c) * 3 + dy]);   // dy in {0,1}; row 2 masked off
    } else if (e < 327680) {
        int e2 = e - 131072;
        int wvg = e2 / 6144, rem = e2 % 6144;
        int wv = wvg >> 2, g = wvg & 3;
        int kt = rem >> 9, l = (rem >> 3) & 63, j = rem & 7;
        int m = 128 * g + 16 * wv + (l & 15);
        int k = kt * 32 + (l >> 4) * 8 + j;
        int d = k >> 7, c = k & 127;
        wsp[e2] = f2bf(w_stos[(m * 128 + c) * 3 + d]);
    }
}

// ---------------- phase 1: input-to-state conv as bf16 MFMA GEMM --------------
// One block per (b,s). fs INCLUDES b_itos+b_stos. Layout:
// fsp[(bs*8+wv)*1024 + (g*4+n)*64 + l], packed bf16 pairs for acc rows r=0..3.
__global__ __launch_bounds__(512, 2) void itos_gemm(
    const float* __restrict__ image, const u16* __restrict__ wip,
    const float* __restrict__ b_itos, const float* __restrict__ b_stos,
    uint2* __restrict__ fsp) {
    const int bs = blockIdx.x, b = bs >> 6, s = bs & 63;
    const int t = threadIdx.x, wv = t >> 6, l = t & 63, lr = l & 15, lk = l >> 4;
    __shared__ u16 ImgT[64 * 256];   // [w][k], k = dy*128+c, XOR-swizzled

    {   // stage rows s-1 (dy=0) and s (dy=1), fp32 -> bf16, transposed
        const int r = t >> 1, half = t & 1;   // r = dy*128 + c
        const int dy = r >> 7, c = r & 127;
        const int s0 = s - 1 + dy;
        float v[32];
        if (s0 >= 0) {
            const float* src = image + (((size_t)b * NC + c) * NS + s0) * NW + half * 32;
            #pragma unroll
            for (int qq = 0; qq < 8; ++qq) {
                float4 f = *(const float4*)(src + 4 * qq);
                v[4*qq] = f.x; v[4*qq+1] = f.y; v[4*qq+2] = f.z; v[4*qq+3] = f.w;
            }
        } else {
            #pragma unroll
            for (int qq = 0; qq < 32; ++qq) v[qq] = 0.f;
        }
        #pragma unroll
        for (int qq = 0; qq < 32; ++qq) {
            int w = half * 32 + qq;
            ImgT[w * 256 + (r ^ ((w & 7) << 3))] = f2bf(v[qq]);
        }
    }
    __syncthreads();

    f32x4 acc[4][4];
    #pragma unroll
    for (int g = 0; g < 4; ++g)
        #pragma unroll
        for (int n = 0; n < 4; ++n) acc[g][n] = (f32x4){0.f, 0.f, 0.f, 0.f};

    #pragma unroll
    for (int kt = 0; kt < 8; ++kt) {
        short8 a[4], bb[4];
        #pragma unroll
        for (int g = 0; g < 4; ++g)
            a[g] = *(const short8*)(wip + (((wv * 4 + g) * 8 + kt) * 64 + l) * 8);
        const int cu = kt * 32 + lk * 8;
        #pragma unroll
        for (int n = 0; n < 4; ++n) {
            const int w = n * 16 + lr;
            bb[n] = *(const short8*)&ImgT[w * 256 + (cu ^ ((w & 7) << 3))];
        }
        #pragma unroll
        for (int g = 0; g < 4; ++g)
            #pragma unroll
            for (int n = 0; n < 4; ++n)
                acc[g][n] = __builtin_amdgcn_mfma_f32_16x16x32_bf16(a[g], bb[n], acc[g][n], 0, 0, 0);
    }

    // fold both biases in (fp32, before bf16 rounding)
    float bias[4][4];
    #pragma unroll
    for (int g = 0; g < 4; ++g)
        #pragma unroll
        for (int r = 0; r < 4; ++r) {
            int m = 128 * g + 16 * wv + lk * 4 + r;
            bias[g][r] = b_itos[m] + b_stos[m];
        }

    uint2* dst = fsp + ((size_t)bs * 8 + wv) * 1024 + l;
    #pragma unroll
    for (int g = 0; g < 4; ++g)
        #pragma unroll
        for (int n = 0; n < 4; ++n) {
            uint2 u;
            u.x = (unsigned)f2bf(acc[g][n][0] + bias[g][0]) | ((unsigned)f2bf(acc[g][n][1] + bias[g][1]) << 16);
            u.y = (unsigned)f2bf(acc[g][n][2] + bias[g][2]) | ((unsigned)f2bf(acc[g][n][3] + bias[g][3]) << 16);
            dst[(g * 4 + n) * 64] = u;
        }
}

// ---------------- phase 2: recurrent, one block per batch, 16 waves -----------
// Wave wv = (vn<<3)|vh: all 4 gates, nh in [16vh,16vh+16), w in [32vn,32vn+32).
// Designed to FIT the hard 64-VGPR budget of 1024-thread blocks:
//   acc 32 + c_r 8 + bb 8 + a 4 (per-gate load) + ptrs ~6  ->  ~58 live.
// fs read directly at acc-init (no persistent prefetch regs). Ht double-buffered,
// XOR-swizzled, single lgkm-only barrier per step (all validated in R6).
__global__ __launch_bounds__(1024) void rowlstm_w16(
    const u16* __restrict__ wsp, const uint2* __restrict__ fsp,
    const float* __restrict__ h0, const float* __restrict__ c0,
    float* __restrict__ out) {
    const int b = blockIdx.x;
    const int t = threadIdx.x, l = t & 63, lr = l & 15, lk = l >> 4;
    const int wv = t >> 6, vh = wv & 7, vn = wv >> 3;
    __shared__ u16 Ht[2 * 8448];   // two buffers: [66][128] u16 each

    // zero the 4 halo rows (wh=0,65 in both buffers)
    if (t < 512) {
        int i = t & 127, z = t >> 7;
        Ht[(z >> 1) * 8448 + ((z & 1) ? 65 : 0) * 128 + i] = 0;
    }
    // h0 into buffer 0 (1024 thr x 8 elems = 8192)
    #pragma unroll
    for (int j = 0; j < 8; ++j) {
        int e = t * 8 + j, nh = e >> 6, w = e & 63, wh = w + 1;
        Ht[wh * 128 + (nh ^ ((wh & 7) << 3))] = f2bf(h0[e]);
    }

    // 8 outputs per lane: nh = 16vh + lk*4 + r, w = 32vn + nn*16 + lr
    float c_r[8];
    #pragma unroll
    for (int nn = 0; nn < 2; ++nn)
        #pragma unroll
        for (int r = 0; r < 4; ++r)
            c_r[nn * 4 + r] = c0[(16 * vh + lk * 4 + r) * 64 + 32 * vn + nn * 16 + lr];

    // single out base pointer; offsets computed per store
    float* outb = out + ((size_t)b * NHH + 16 * vh + lk * 4) * (NS * NW) + 32 * vn + lr;

    const u16* wbase = wsp + vh * 24576;                      // 4g*12kt*64l*8
    const uint2* fsb = fsp + ((size_t)b * 512 + vh) * 1024 + l;

    __syncthreads();

    unsigned cur = 0;
    for (int s = 0; s < NS; ++s) {
        // fs direct read (bias folded in at itos time) -> accumulator init.
        // Loads issue first; the wait overlaps with kt0's weight loads below.
        f32x4 acc[4][2];
        {
            uint2 fsv[8];
            #pragma unroll
            for (int g = 0; g < 4; ++g)
                #pragma unroll
                for (int nn = 0; nn < 2; ++nn)
                    fsv[g * 2 + nn] = fsb[(size_t)s * 8192 + (g * 4 + 2 * vn + nn) * 64];
            #pragma unroll
            for (int g = 0; g < 4; ++g)
                #pragma unroll
                for (int nn = 0; nn < 2; ++nn)
                    #pragma unroll
                    for (int r = 0; r < 4; ++r)
                        acc[g][nn][r] = bfreg(fsv[g * 2 + nn], r);
        }

        #pragma unroll
        for (int kt = 0; kt < 12; ++kt) {
            const int d = kt >> 2, kc = kt & 3;
            const int cu = kc * 32 + lk * 8;
            short8 bb[2];
            #pragma unroll
            for (int nn = 0; nn < 2; ++nn) {
                const int wh = (2 * vn + nn) * 16 + lr + d;   // h index = wh-1 = w+d-1
                bb[nn] = *(const short8*)&Ht[cur + wh * 128 + (cu ^ ((wh & 7) << 3))];
            }
            #pragma unroll
            for (int g = 0; g < 4; ++g) {
                short8 a = *(const short8*)(wbase + ((g * 12 + kt) * 64 + l) * 8);
                acc[g][0] = __builtin_amdgcn_mfma_f32_16x16x32_bf16(a, bb[0], acc[g][0], 0, 0, 0);
                acc[g][1] = __builtin_amdgcn_mfma_f32_16x16x32_bf16(a, bb[1], acc[g][1], 0, 0, 0);
            }
        }

        // in-wave gating epilogue; h_new = c_OLD * sigmoid(o)
        const unsigned nxt = cur ^ 8448;
        #pragma unroll
        for (int nn = 0; nn < 2; ++nn) {
            u16 hb[4];
            #pragma unroll
            for (int r = 0; r < 4; ++r) {
                const float si = fsig(acc[0][nn][r]);
                const float tg = ftanh(acc[1][nn][r]);
                const float sf = fsig(acc[2][nn][r]);
                const float so = fsig(acc[3][nn][r]);
                const float cold = c_r[nn * 4 + r];
                c_r[nn * 4 + r] = sf * cold + si * tg;
                const float hn = cold * so;
                outb[(size_t)r * (NS * NW) + s * NW + nn * 16] = hn;
                hb[r] = f2bf(hn);
            }
            uint2 hw;
            hw.x = (unsigned)hb[0] | ((unsigned)hb[1] << 16);
            hw.y = (unsigned)hb[2] | ((unsigned)hb[3] << 16);
            const int nh0 = 16 * vh + lk * 4;
            const int wh = 32 * vn + nn * 16 + lr + 1;
            *(uint2*)&Ht[nxt + wh * 128 + (nh0 ^ ((wh & 7) << 3))] = hw;
        }

        // single barrier per step: drain LDS only, vmem stays in flight
        asm volatile("s_waitcnt lgkmcnt(0)" ::: "memory");
        __builtin_amdgcn_s_barrier();
        asm volatile("" ::: "memory");
        cur = nxt;
    }
}

// ---------------- fallback (validated round-1 fp32 kernel) --------------------
__global__ __launch_bounds__(512, 2) void rowlstm_f32(
    const float* __restrict__ image, const float* __restrict__ w_itos,
    const float* __restrict__ b_itos, const float* __restrict__ w_stos,
    const float* __restrict__ b_stos, const float* __restrict__ h0,
    const float* __restrict__ c0, float* __restrict__ out) {
    const int b = blockIdx.x, t = threadIdx.x, wq = t & 3, nh = t >> 2, w0 = wq * 16;
    __shared__ float h_lds[NHH][NW + 2];
    #pragma unroll
    for (int j = 0; j < 16; ++j) h_lds[nh][1 + w0 + j] = h0[nh * NW + w0 + j];
    if (wq == 0) { h_lds[nh][0] = 0.f; h_lds[nh][NW + 1] = 0.f; }
    float c_r[16];
    #pragma unroll
    for (int j = 0; j < 16; ++j) c_r[j] = c0[nh * NW + w0 + j];
    const float bias[4] = {
        b_itos[0 * NHH + nh] + b_stos[0 * NHH + nh], b_itos[1 * NHH + nh] + b_stos[1 * NHH + nh],
        b_itos[2 * NHH + nh] + b_stos[2 * NHH + nh], b_itos[3 * NHH + nh] + b_stos[3 * NHH + nh]};
    const float* img_b = image + (size_t)b * NC * NS * NW;
    __syncthreads();
    for (int s = 0; s < NS; ++s) {
        float acc[4][16];
        #pragma unroll
        for (int g = 0; g < 4; ++g)
            #pragma unroll
            for (int j = 0; j < 16; ++j) acc[g][j] = bias[g];
        #pragma unroll 2
        for (int ci = 0; ci < NC; ++ci) {
            float imp[16], imc[16];
            const float* iprow = img_b + ((size_t)ci * NS + s) * NW + w0;
            #pragma unroll
            for (int qq = 0; qq < 4; ++qq) {
                float4 vv = *(const float4*)(iprow + 4 * qq);
                imc[4*qq] = vv.x; imc[4*qq+1] = vv.y; imc[4*qq+2] = vv.z; imc[4*qq+3] = vv.w;
            }
            if (s > 0) {
                #pragma unroll
                for (int qq = 0; qq < 4; ++qq) {
                    float4 vv = *(const float4*)(iprow - NW + 4 * qq);
                    imp[4*qq] = vv.x; imp[4*qq+1] = vv.y; imp[4*qq+2] = vv.z; imp[4*qq+3] = vv.w;
                }
            } else {
                #pragma unroll
                for (int j = 0; j < 16; ++j) imp[j] = 0.f;
            }
            float hv[18];
            #pragma unroll
            for (int j = 0; j < 18; ++j) hv[j] = h_lds[ci][w0 + j];
            const float* wip2 = w_itos + ((size_t)nh * NC + ci) * 3;
            const float* wsp2 = w_stos + ((size_t)nh * NHH + ci) * 3;
            #pragma unroll
            for (int g = 0; g < 4; ++g) {
                const float wi0 = wip2[(size_t)g * GSTR + 0], wi1 = wip2[(size_t)g * GSTR + 1];
                const float ws0 = wsp2[(size_t)g * GSTR + 0], ws1 = wsp2[(size_t)g * GSTR + 1],
                            ws2 = wsp2[(size_t)g * GSTR + 2];
                #pragma unroll
                for (int j = 0; j < 16; ++j)
                    acc[g][j] += wi0 * imp[j] + wi1 * imc[j] + ws0 * hv[j] + ws1 * hv[j+1] + ws2 * hv[j+2];
            }
        }
        float hn[16];
        #pragma unroll
        for (int j = 0; j < 16; ++j) {
            const float si = 1.f / (1.f + __expf(-acc[0][j]));
            const float tg = tanhf(acc[1][j]);
            const float sf = 1.f / (1.f + __expf(-acc[2][j]));
            const float so = 1.f / (1.f + __expf(-acc[3][j]));
            const float cold = c_r[j];
            c_r[j] = sf * cold + si * tg;
            hn[j] = cold * so;
        }
        __syncthreads();
        #pragma unroll
        for (int j = 0; j < 16; ++j) h_lds[nh][1 + w0 + j] = hn[j];
        float* opp = out + (((size_t)b * NHH + nh) * NS + s) * NW + w0;
        #pragma unroll
        for (int qq = 0; qq < 4; ++qq)
            *(float4*)(opp + 4 * qq) = make_float4(hn[4*qq], hn[4*qq+1], hn[4*qq+2], hn[4*qq+3]);
        __syncthreads();
    }
}

extern "C" void kernel_launch(void* const* d_in, const int* in_sizes, int n_in,
                              void* d_out, int out_size, void* d_ws, size_t ws_size,
                              hipStream_t stream) {
    const float* image  = (const float*)d_in[0];
    const float* w_itos = (const float*)d_in[1];
    const float* b_itos = (const float*)d_in[2];
    const float* w_stos = (const float*)d_in[3];
    const float* b_stos = (const float*)d_in[4];
    const float* h0     = (const float*)d_in[5];
    const float* c0     = (const float*)d_in[6];
    float* out = (float*)d_out;

    if (ws_size >= WS_NEEDED) {
        u16*  wip = (u16*)((char*)d_ws + WI_OFF);
        u16*  wsp = (u16*)((char*)d_ws + WS_OFF);
        uint2* fsp = (uint2*)((char*)d_ws + FS_OFF);
        pack_weights<<<1280, 256, 0, stream>>>(w_itos, w_stos, wip, wsp);
        itos_gemm<<<1024, 512, 0, stream>>>(image, wip, b_itos, b_stos, fsp);
        rowlstm_w16<<<NB, 1024, 0, stream>>>(wsp, fsp, h0, c0, out);
    } else {
        rowlstm_f32<<<NB, 512, 0, stream>>>(image, w_itos, b_itos, w_stos, b_stos, h0, c0, out);
    }
}

// Round 8
// 1202.776 us; speedup vs baseline: 1.0439x; 1.0439x over previous
//
#include <hip/hip_runtime.h>
#include <cmath>

typedef __attribute__((ext_vector_type(8))) short short8;
typedef __attribute__((ext_vector_type(4))) float f32x4;
typedef _Float16 h4 __attribute__((ext_vector_type(4)));
typedef unsigned short u16;

#define NB   16
#define NC   128
#define NS   64
#define NW   64
#define NHH  128
#define GSTR (NHH * NC * 3)

// workspace layout (bytes)
#define WI_OFF   0u          // Wi packed: 512*256*2 = 262144
#define WS_OFF   262144u     // Ws packed: 512*384*2 = 393216 (ends 655360)
#define FLAG_OFF 655360u     // cnt[b*64+s] uint32: 4 KB
#define HX_OFF   786432u     // hx[b][2][64][128] u16 = 512 KB
#define FS_OFF   2097152u    // fs (bias included): 1024*512*64*2 = 67108864
#define WS_NEEDED (FS_OFF + (size_t)NB * NS * 512 * NW * 2)

__device__ __forceinline__ u16 f2bf(float f) {
    unsigned u = __builtin_bit_cast(unsigned, f);
    u += 0x7fffu + ((u >> 16) & 1u);
    return (u16)(u >> 16);
}
__device__ __forceinline__ float bfreg(uint2 u, int r) {
    unsigned w = (r < 2) ? u.x : u.y;
    unsigned bits = (r & 1) ? (w & 0xffff0000u) : (w << 16);
    return __builtin_bit_cast(float, bits);
}
__device__ __forceinline__ float fsig(float x) {
    return __builtin_amdgcn_rcpf(1.f + __builtin_amdgcn_exp2f(x * -1.442695041f));
}
__device__ __forceinline__ float ftanh(float x) {
    return 1.f - 2.f * __builtin_amdgcn_rcpf(1.f + __builtin_amdgcn_exp2f(x * 2.885390082f));
}

// ---------------- phase 0: pack weights into MFMA A-fragment layout (bf16) ----
// Wi: wip[(((W*4+g)*8+kt)*64+l)*8+j],  m=128g+16W+(l&15), k=kt*32+(l>>4)*8+j -> (dy,c)
// Ws: wsp[(((W*4+g)*12+kt)*64+l)*8+j], m=128g+16W+(l&15), k -> (d=k>>7, c=k&127)
__global__ void pack_weights(const float* __restrict__ w_itos,
                             const float* __restrict__ w_stos,
                             u16* __restrict__ wip, u16* __restrict__ wsp) {
    int e = blockIdx.x * 256 + threadIdx.x;
    if (e < 131072) {
        int j = e & 7, l = (e >> 3) & 63, kt = (e >> 9) & 7, wvg = e >> 12;
        int wv = wvg >> 2, g = wvg & 3;
        int m = 128 * g + 16 * wv + (l & 15);
        int k = kt * 32 + (l >> 4) * 8 + j;
        int dy = k >> 7, c = k & 127;
        wip[e] = f2bf(w_itos[(m * 128 + c) * 3 + dy]);   // dy in {0,1}; row 2 masked off
    } else if (e < 327680) {
        int e2 = e - 131072;
        int wvg = e2 / 6144, rem = e2 % 6144;
        int wv = wvg >> 2, g = wvg & 3;
        int kt = rem >> 9, l = (rem >> 3) & 63, j = rem & 7;
        int m = 128 * g + 16 * wv + (l & 15);
        int k = kt * 32 + (l >> 4) * 8 + j;
        int d = k >> 7, c = k & 127;
        wsp[e2] = f2bf(w_stos[(m * 128 + c) * 3 + d]);
    }
}

// ---------------- phase 1: input-to-state conv as bf16 MFMA GEMM --------------
// One block per (b,s). fs INCLUDES b_itos+b_stos. Layout:
// fsp[(bs*8+W)*1024 + (g*4+n)*64 + l], packed bf16 pairs for acc rows r=0..3.
__global__ __launch_bounds__(512, 2) void itos_gemm(
    const float* __restrict__ image, const u16* __restrict__ wip,
    const float* __restrict__ b_itos, const float* __restrict__ b_stos,
    uint2* __restrict__ fsp) {
    const int bs = blockIdx.x, b = bs >> 6, s = bs & 63;
    const int t = threadIdx.x, wv = t >> 6, l = t & 63, lr = l & 15, lk = l >> 4;
    __shared__ u16 ImgT[64 * 256];   // [w][k], k = dy*128+c, XOR-swizzled

    {   // stage rows s-1 (dy=0) and s (dy=1), fp32 -> bf16, transposed
        const int r = t >> 1, half = t & 1;   // r = dy*128 + c
        const int dy = r >> 7, c = r & 127;
        const int s0 = s - 1 + dy;
        float v[32];
        if (s0 >= 0) {
            const float* src = image + (((size_t)b * NC + c) * NS + s0) * NW + half * 32;
            #pragma unroll
            for (int qq = 0; qq < 8; ++qq) {
                float4 f = *(const float4*)(src + 4 * qq);
                v[4*qq] = f.x; v[4*qq+1] = f.y; v[4*qq+2] = f.z; v[4*qq+3] = f.w;
            }
        } else {
            #pragma unroll
            for (int qq = 0; qq < 32; ++qq) v[qq] = 0.f;
        }
        #pragma unroll
        for (int qq = 0; qq < 32; ++qq) {
            int w = half * 32 + qq;
            ImgT[w * 256 + (r ^ ((w & 7) << 3))] = f2bf(v[qq]);
        }
    }
    __syncthreads();

    f32x4 acc[4][4];
    #pragma unroll
    for (int g = 0; g < 4; ++g)
        #pragma unroll
        for (int n = 0; n < 4; ++n) acc[g][n] = (f32x4){0.f, 0.f, 0.f, 0.f};

    #pragma unroll
    for (int kt = 0; kt < 8; ++kt) {
        short8 a[4], bb[4];
        #pragma unroll
        for (int g = 0; g < 4; ++g)
            a[g] = *(const short8*)(wip + (((wv * 4 + g) * 8 + kt) * 64 + l) * 8);
        const int cu = kt * 32 + lk * 8;
        #pragma unroll
        for (int n = 0; n < 4; ++n) {
            const int w = n * 16 + lr;
            bb[n] = *(const short8*)&ImgT[w * 256 + (cu ^ ((w & 7) << 3))];
        }
        #pragma unroll
        for (int g = 0; g < 4; ++g)
            #pragma unroll
            for (int n = 0; n < 4; ++n)
                acc[g][n] = __builtin_amdgcn_mfma_f32_16x16x32_bf16(a[g], bb[n], acc[g][n], 0, 0, 0);
    }

    float bias[4][4];
    #pragma unroll
    for (int g = 0; g < 4; ++g)
        #pragma unroll
        for (int r = 0; r < 4; ++r) {
            int m = 128 * g + 16 * wv + lk * 4 + r;
            bias[g][r] = b_itos[m] + b_stos[m];
        }

    uint2* dst = fsp + ((size_t)bs * 8 + wv) * 1024 + l;
    #pragma unroll
    for (int g = 0; g < 4; ++g)
        #pragma unroll
        for (int n = 0; n < 4; ++n) {
            uint2 u;
            u.x = (unsigned)f2bf(acc[g][n][0] + bias[g][0]) | ((unsigned)f2bf(acc[g][n][1] + bias[g][1]) << 16);
            u.y = (unsigned)f2bf(acc[g][n][2] + bias[g][2]) | ((unsigned)f2bf(acc[g][n][3] + bias[g][3]) << 16);
            dst[(g * 4 + n) * 64] = u;
        }
}

// ---------------- phase 2: recurrent, M-split 4-way, weights in registers -----
// 64 blocks: bid = mo*16 + b. Block mo owns nh in [32mo,32mo+32), all gates.
// 8 waves: wv = mq*2+vp. Wave: m-tiles {2mq,2mq+1} (mt=hh*4+g), n-tiles {2vp,2vp+1}.
// Weights (2 mt x 12 kt x 16B = 96 VGPR) loaded ONCE, reused all 64 steps.
// Preacts exchanged via f16 LDS plane; h exchanged cross-block via hx + flag.
__global__ __launch_bounds__(512, 2) void rowlstm_ms(
    const u16* __restrict__ wsp, const uint2* __restrict__ fsp,
    const float* __restrict__ h0, const float* __restrict__ c0,
    unsigned* __restrict__ cnt, u16* __restrict__ hx,
    float* __restrict__ out) {
    const int bid = blockIdx.x;
    const int b = bid & 15, mo = bid >> 4;
    const int t = threadIdx.x, wv = t >> 6, l = t & 63, lr = l & 15, lk = l >> 4;
    const int mq = wv >> 1, vp = wv & 1;

    __shared__ u16 Ht[66 * 128];       // [wh][nh^swz] bf16, rows 0/65 zero halo
    __shared__ u16 pre[4 * 64 * 32];   // [g][w][nhl^swz] f16

    // halo rows
    if (t < 256) { int i = t & 127; Ht[((t >> 7) ? 65 : 0) * 128 + i] = 0; }
    // full h0 into Ht
    #pragma unroll
    for (int j = 0; j < 16; ++j) {
        int e = t * 16 + j, nh = e >> 6, w = e & 63, wh = w + 1;
        Ht[wh * 128 + (nh ^ ((wh & 7) << 3))] = f2bf(h0[e]);
    }

    // persistent weight registers: wr[mi][kt]
    short8 wr[2][12];
    #pragma unroll
    for (int mi = 0; mi < 2; ++mi) {
        const int mt = 2 * mq + mi, hh = mt >> 2, g = mt & 3, W = 2 * mo + hh;
        #pragma unroll
        for (int kt = 0; kt < 12; ++kt)
            wr[mi][kt] = *(const short8*)(wsp + (((W * 4 + g) * 12 + kt) * 64 + l) * 8);
    }

    // epilogue ownership: w = t&63, local nh block nhl4 = t>>6 (4 rows each)
    const int wE = t & 63, nhl4 = t >> 6;
    float c_r[4];
    #pragma unroll
    for (int r = 0; r < 4; ++r)
        c_r[r] = c0[(32 * mo + nhl4 * 4 + r) * 64 + wE];
    float* outb = out + ((size_t)b * NHH + 32 * mo + nhl4 * 4) * (NS * NW) + wE;

    __syncthreads();

    unsigned done = 0;   // steps completed marker not needed; loop below
    (void)done;

    for (int s = 0; s < NS; ++s) {
        const int p = (s + 1) & 1;
        // ---- A: GEMM. acc init from fs (bias folded in). ----
        f32x4 acc[2][2];
        #pragma unroll
        for (int mi = 0; mi < 2; ++mi) {
            const int mt = 2 * mq + mi, hh = mt >> 2, g = mt & 3;
            const uint2* fb = fsp + ((size_t)(b * 64 + s) * 8 + 2 * mo + hh) * 1024 + l;
            #pragma unroll
            for (int ni = 0; ni < 2; ++ni) {
                uint2 fv = fb[(g * 4 + 2 * vp + ni) * 64];
                #pragma unroll
                for (int r = 0; r < 4; ++r) acc[mi][ni][r] = bfreg(fv, r);
            }
        }

        #pragma unroll
        for (int kt = 0; kt < 12; ++kt) {
            const int d = kt >> 2, kc = kt & 3;
            const int cu = kc * 32 + lk * 8;
            short8 bb[2];
            #pragma unroll
            for (int ni = 0; ni < 2; ++ni) {
                const int wh = (2 * vp + ni) * 16 + lr + d;   // h index = wh-1 = w+d-1
                bb[ni] = *(const short8*)&Ht[wh * 128 + (cu ^ ((wh & 7) << 3))];
            }
            #pragma unroll
            for (int mi = 0; mi < 2; ++mi)
                #pragma unroll
                for (int ni = 0; ni < 2; ++ni)
                    acc[mi][ni] = __builtin_amdgcn_mfma_f32_16x16x32_bf16(wr[mi][kt], bb[ni], acc[mi][ni], 0, 0, 0);
        }

        // ---- B: preacts -> f16 plane ----
        #pragma unroll
        for (int mi = 0; mi < 2; ++mi) {
            const int mt = 2 * mq + mi, hh = mt >> 2, g = mt & 3;
            const int nhl0 = 16 * hh + lk * 4;
            #pragma unroll
            for (int ni = 0; ni < 2; ++ni) {
                const int w = (2 * vp + ni) * 16 + lr;
                h4 ph;
                #pragma unroll
                for (int r = 0; r < 4; ++r) ph[r] = (_Float16)acc[mi][ni][r];
                *(h4*)&pre[(g * 64 + w) * 32 + (nhl0 ^ (4 * (w & 7)))] = ph;
            }
        }
        asm volatile("s_waitcnt lgkmcnt(0)" ::: "memory");
        __builtin_amdgcn_s_barrier();
        asm volatile("" ::: "memory");

        // ---- C: epilogue (4 outputs per thread); h_new = c_OLD * sigmoid(o) ----
        h4 P[4];
        #pragma unroll
        for (int g = 0; g < 4; ++g)
            P[g] = *(const h4*)&pre[(g * 64 + wE) * 32 + ((nhl4 * 4) ^ (4 * (wE & 7)))];
        u16 hb[4];
        #pragma unroll
        for (int r = 0; r < 4; ++r) {
            const float si = fsig((float)P[0][r]);
            const float tg = ftanh((float)P[1][r]);
            const float sf = fsig((float)P[2][r]);
            const float so = fsig((float)P[3][r]);
            const float cold = c_r[r];
            c_r[r] = sf * cold + si * tg;
            const float hn = cold * so;
            outb[(size_t)r * (NS * NW) + s * NW] = hn;
            hb[r] = f2bf(hn);
        }
        {   // write own h-slice to hx (pre-swizzled in Ht layout)
            const int whE = wE + 1;
            const int nh0 = 32 * mo + nhl4 * 4;
            uint2 hw;
            hw.x = (unsigned)hb[0] | ((unsigned)hb[1] << 16);
            hw.y = (unsigned)hb[2] | ((unsigned)hb[3] << 16);
            *(uint2*)&hx[(size_t)(b * 2 + p) * 8192 + wE * 128 + (nh0 ^ ((whE & 7) << 3))] = hw;
        }

        if (s < NS - 1) {
            // ---- D: cross-block sync ----
            __threadfence();               // agent-scope release of hx stores
            __syncthreads();
            if (t == 0) {
                unsigned* f = cnt + (b * 64 + s);
                __hip_atomic_fetch_add(f, 1u, __ATOMIC_ACQ_REL, __HIP_MEMORY_SCOPE_AGENT);
                while (__hip_atomic_load(f, __ATOMIC_ACQUIRE, __HIP_MEMORY_SCOPE_AGENT) < 4u) {}
            }
            __syncthreads();
            // ---- E: rebuild Ht from hx (straight copy; hx is pre-swizzled) ----
            {
                const int row = t >> 3;                 // w row 0..63
                const int ch  = (t & 7) ^ (row & 7);    // bank-spread chunk
                const uint4* src = (const uint4*)&hx[(size_t)(b * 2 + p) * 8192 + row * 128 + ch * 16];
                uint4 v0 = src[0], v1 = src[1];
                *(uint4*)&Ht[(row + 1) * 128 + ch * 16]     = v0;
                *(uint4*)&Ht[(row + 1) * 128 + ch * 16 + 8] = v1;
            }
            asm volatile("s_waitcnt lgkmcnt(0)" ::: "memory");
            __builtin_amdgcn_s_barrier();
            asm volatile("" ::: "memory");
        }
    }
}

// ---------------- fallback (validated round-1 fp32 kernel) --------------------
__global__ __launch_bounds__(512, 2) void rowlstm_f32(
    const float* __restrict__ image, const float* __restrict__ w_itos,
    const float* __restrict__ b_itos, const float* __restrict__ w_stos,
    const float* __restrict__ b_stos, const float* __restrict__ h0,
    const float* __restrict__ c0, float* __restrict__ out) {
    const int b = blockIdx.x, t = threadIdx.x, wq = t & 3, nh = t >> 2, w0 = wq * 16;
    __shared__ float h_lds[NHH][NW + 2];
    #pragma unroll
    for (int j = 0; j < 16; ++j) h_lds[nh][1 + w0 + j] = h0[nh * NW + w0 + j];
    if (wq == 0) { h_lds[nh][0] = 0.f; h_lds[nh][NW + 1] = 0.f; }
    float c_r[16];
    #pragma unroll
    for (int j = 0; j < 16; ++j) c_r[j] = c0[nh * NW + w0 + j];
    const float bias[4] = {
        b_itos[0 * NHH + nh] + b_stos[0 * NHH + nh], b_itos[1 * NHH + nh] + b_stos[1 * NHH + nh],
        b_itos[2 * NHH + nh] + b_stos[2 * NHH + nh], b_itos[3 * NHH + nh] + b_stos[3 * NHH + nh]};
    const float* img_b = image + (size_t)b * NC * NS * NW;
    __syncthreads();
    for (int s = 0; s < NS; ++s) {
        float acc[4][16];
        #pragma unroll
        for (int g = 0; g < 4; ++g)
            #pragma unroll
            for (int j = 0; j < 16; ++j) acc[g][j] = bias[g];
        #pragma unroll 2
        for (int ci = 0; ci < NC; ++ci) {
            float imp[16], imc[16];
            const float* iprow = img_b + ((size_t)ci * NS + s) * NW + w0;
            #pragma unroll
            for (int qq = 0; qq < 4; ++qq) {
                float4 vv = *(const float4*)(iprow + 4 * qq);
                imc[4*qq] = vv.x; imc[4*qq+1] = vv.y; imc[4*qq+2] = vv.z; imc[4*qq+3] = vv.w;
            }
            if (s > 0) {
                #pragma unroll
                for (int qq = 0; qq < 4; ++qq) {
                    float4 vv = *(const float4*)(iprow - NW + 4 * qq);
                    imp[4*qq] = vv.x; imp[4*qq+1] = vv.y; imp[4*qq+2] = vv.z; imp[4*qq+3] = vv.w;
                }
            } else {
                #pragma unroll
                for (int j = 0; j < 16; ++j) imp[j] = 0.f;
            }
            float hv[18];
            #pragma unroll
            for (int j = 0; j < 18; ++j) hv[j] = h_lds[ci][w0 + j];
            const float* wip2 = w_itos + ((size_t)nh * NC + ci) * 3;
            const float* wsp2 = w_stos + ((size_t)nh * NHH + ci) * 3;
            #pragma unroll
            for (int g = 0; g < 4; ++g) {
                const float wi0 = wip2[(size_t)g * GSTR + 0], wi1 = wip2[(size_t)g * GSTR + 1];
                const float ws0 = wsp2[(size_t)g * GSTR + 0], ws1 = wsp2[(size_t)g * GSTR + 1],
                            ws2 = wsp2[(size_t)g * GSTR + 2];
                #pragma unroll
                for (int j = 0; j < 16; ++j)
                    acc[g][j] += wi0 * imp[j] + wi1 * imc[j] + ws0 * hv[j] + ws1 * hv[j+1] + ws2 * hv[j+2];
            }
        }
        float hn[16];
        #pragma unroll
        for (int j = 0; j < 16; ++j) {
            const float si = 1.f / (1.f + __expf(-acc[0][j]));
            const float tg = tanhf(acc[1][j]);
            const float sf = 1.f / (1.f + __expf(-acc[2][j]));
            const float so = 1.f / (1.f + __expf(-acc[3][j]));
            const float cold = c_r[j];
            c_r[j] = sf * cold + si * tg;
            hn[j] = cold * so;
        }
        __syncthreads();
        #pragma unroll
        for (int j = 0; j < 16; ++j) h_lds[nh][1 + w0 + j] = hn[j];
        float* opp = out + (((size_t)b * NHH + nh) * NS + s) * NW + w0;
        #pragma unroll
        for (int qq = 0; qq < 4; ++qq)
            *(float4*)(opp + 4 * qq) = make_float4(hn[4*qq], hn[4*qq+1], hn[4*qq+2], hn[4*qq+3]);
        __syncthreads();
    }
}

extern "C" void kernel_launch(void* const* d_in, const int* in_sizes, int n_in,
                              void* d_out, int out_size, void* d_ws, size_t ws_size,
                              hipStream_t stream) {
    const float* image  = (const float*)d_in[0];
    const float* w_itos = (const float*)d_in[1];
    const float* b_itos = (const float*)d_in[2];
    const float* w_stos = (const float*)d_in[3];
    const float* b_stos = (const float*)d_in[4];
    const float* h0     = (const float*)d_in[5];
    const float* c0     = (const float*)d_in[6];
    float* out = (float*)d_out;

    if (ws_size >= WS_NEEDED) {
        u16*      wip = (u16*)((char*)d_ws + WI_OFF);
        u16*      wsp = (u16*)((char*)d_ws + WS_OFF);
        unsigned* cnt = (unsigned*)((char*)d_ws + FLAG_OFF);
        u16*      hx  = (u16*)((char*)d_ws + HX_OFF);
        uint2*    fsp = (uint2*)((char*)d_ws + FS_OFF);
        hipMemsetAsync((char*)d_ws + FLAG_OFF, 0, 4096, stream);
        pack_weights<<<1280, 256, 0, stream>>>(w_itos, w_stos, wip, wsp);
        itos_gemm<<<1024, 512, 0, stream>>>(image, wip, b_itos, b_stos, fsp);
        rowlstm_ms<<<64, 512, 0, stream>>>(wsp, fsp, h0, c0, cnt, hx, out);
    } else {
        rowlstm_f32<<<NB, 512, 0, stream>>>(image, w_itos, b_itos, w_stos, b_stos, h0, c0, out);
    }
}

// Round 10
// 956.901 us; speedup vs baseline: 1.3121x; 1.2569x over previous
//
#include <hip/hip_runtime.h>
#include <cmath>

typedef __attribute__((ext_vector_type(8))) short short8;
typedef __attribute__((ext_vector_type(4))) float f32x4;
typedef unsigned short u16;

#define NB   16
#define NC   128
#define NS   64
#define NW   64
#define NHH  128
#define GSTR (NHH * NC * 3)

// workspace layout (bytes)
#define WI_OFF 0u            // Wi packed: 512*256*2 = 262144
#define WS_OFF 262144u       // Ws packed: 512*384*2 = 393216
#define FS_OFF 1048576u      // fs (bias included): 1024 * 512*64 * 2 = 67108864
#define WS_NEEDED (FS_OFF + (size_t)NB * NS * 512 * NW * 2)

__device__ __forceinline__ u16 f2bf(float f) {
    unsigned u = __builtin_bit_cast(unsigned, f);
    u += 0x7fffu + ((u >> 16) & 1u);
    return (u16)(u >> 16);
}
__device__ __forceinline__ float bfreg(uint2 u, int r) {
    unsigned w = (r < 2) ? u.x : u.y;
    unsigned bits = (r & 1) ? (w & 0xffff0000u) : (w << 16);
    return __builtin_bit_cast(float, bits);
}
__device__ __forceinline__ float fsig(float x) {
    return __builtin_amdgcn_rcpf(1.f + __builtin_amdgcn_exp2f(x * -1.442695041f));
}
__device__ __forceinline__ float ftanh(float x) {
    return 1.f - 2.f * __builtin_amdgcn_rcpf(1.f + __builtin_amdgcn_exp2f(x * 2.885390082f));
}
// MFMA with accumulator FORCED into AGPRs (dodges the 64-arch-VGPR cap of
// 1024-thread blocks; gfx950 per-SIMD file fits 4 waves x (64V+32A)).
__device__ __forceinline__ void mfma_a(f32x4& acc, short8 a, short8 b) {
    asm volatile("v_mfma_f32_16x16x32_bf16 %0, %1, %2, %0"
                 : "+a"(acc) : "v"(a), "v"(b));
}
// Hazard pads that CARRY DEPENDENCIES on the accumulators (R9's bare s_nop
// pads had none, so the scheduler hoisted accvgpr reads/writes across them).
#define ACC_PAD1(A) asm volatile("s_nop 7" \
    : "+a"(A[0][0]), "+a"(A[0][1]), "+a"(A[1][0]), "+a"(A[1][1]), \
      "+a"(A[2][0]), "+a"(A[2][1]), "+a"(A[3][0]), "+a"(A[3][1]))
#define ACC_PAD2(A) asm volatile("s_nop 7\ns_nop 7" \
    : "+a"(A[0][0]), "+a"(A[0][1]), "+a"(A[1][0]), "+a"(A[1][1]), \
      "+a"(A[2][0]), "+a"(A[2][1]), "+a"(A[3][0]), "+a"(A[3][1]))

// ---------------- phase 0: pack weights into MFMA A-fragment layout (bf16) ----
// Wi: wip[(((W*4+g)*8+kt)*64+l)*8+j],  m=128g+16W+(l&15), k=kt*32+(l>>4)*8+j -> (dy,c)
// Ws: wsp[(((W*4+g)*12+kt)*64+l)*8+j], m=128g+16W+(l&15), k -> (d=k>>7, c=k&127)
__global__ void pack_weights(const float* __restrict__ w_itos,
                             const float* __restrict__ w_stos,
                             u16* __restrict__ wip, u16* __restrict__ wsp) {
    int e = blockIdx.x * 256 + threadIdx.x;
    if (e < 131072) {
        int j = e & 7, l = (e >> 3) & 63, kt = (e >> 9) & 7, wvg = e >> 12;
        int wv = wvg >> 2, g = wvg & 3;
        int m = 128 * g + 16 * wv + (l & 15);
        int k = kt * 32 + (l >> 4) * 8 + j;
        int dy = k >> 7, c = k & 127;
        wip[e] = f2bf(w_itos[(m * 128 + c) * 3 + dy]);   // dy in {0,1}; row 2 masked off
    } else if (e < 327680) {
        int e2 = e - 131072;
        int wvg = e2 / 6144, rem = e2 % 6144;
        int wv = wvg >> 2, g = wvg & 3;
        int kt = rem >> 9, l = (rem >> 3) & 63, j = rem & 7;
        int m = 128 * g + 16 * wv + (l & 15);
        int k = kt * 32 + (l >> 4) * 8 + j;
        int d = k >> 7, c = k & 127;
        wsp[e2] = f2bf(w_stos[(m * 128 + c) * 3 + d]);
    }
}

// ---------------- phase 1: input-to-state conv as bf16 MFMA GEMM --------------
// One block per (b,s). fs INCLUDES b_itos+b_stos. Layout:
// fsp[(bs*8+W)*1024 + (g*4+n)*64 + l], packed bf16 pairs for acc rows r=0..3.
__global__ __launch_bounds__(512, 2) void itos_gemm(
    const float* __restrict__ image, const u16* __restrict__ wip,
    const float* __restrict__ b_itos, const float* __restrict__ b_stos,
    uint2* __restrict__ fsp) {
    const int bs = blockIdx.x, b = bs >> 6, s = bs & 63;
    const int t = threadIdx.x, wv = t >> 6, l = t & 63, lr = l & 15, lk = l >> 4;
    __shared__ u16 ImgT[64 * 256];   // [w][k], k = dy*128+c, XOR-swizzled

    {   // stage rows s-1 (dy=0) and s (dy=1), fp32 -> bf16, transposed
        const int r = t >> 1, half = t & 1;   // r = dy*128 + c
        const int dy = r >> 7, c = r & 127;
        const int s0 = s - 1 + dy;
        float v[32];
        if (s0 >= 0) {
            const float* src = image + (((size_t)b * NC + c) * NS + s0) * NW + half * 32;
            #pragma unroll
            for (int qq = 0; qq < 8; ++qq) {
                float4 f = *(const float4*)(src + 4 * qq);
                v[4*qq] = f.x; v[4*qq+1] = f.y; v[4*qq+2] = f.z; v[4*qq+3] = f.w;
            }
        } else {
            #pragma unroll
            for (int qq = 0; qq < 32; ++qq) v[qq] = 0.f;
        }
        #pragma unroll
        for (int qq = 0; qq < 32; ++qq) {
            int w = half * 32 + qq;
            ImgT[w * 256 + (r ^ ((w & 7) << 3))] = f2bf(v[qq]);
        }
    }
    __syncthreads();

    f32x4 acc[4][4];
    #pragma unroll
    for (int g = 0; g < 4; ++g)
        #pragma unroll
        for (int n = 0; n < 4; ++n) acc[g][n] = (f32x4){0.f, 0.f, 0.f, 0.f};

    #pragma unroll
    for (int kt = 0; kt < 8; ++kt) {
        short8 a[4], bb[4];
        #pragma unroll
        for (int g = 0; g < 4; ++g)
            a[g] = *(const short8*)(wip + (((wv * 4 + g) * 8 + kt) * 64 + l) * 8);
        const int cu = kt * 32 + lk * 8;
        #pragma unroll
        for (int n = 0; n < 4; ++n) {
            const int w = n * 16 + lr;
            bb[n] = *(const short8*)&ImgT[w * 256 + (cu ^ ((w & 7) << 3))];
        }
        #pragma unroll
        for (int g = 0; g < 4; ++g)
            #pragma unroll
            for (int n = 0; n < 4; ++n)
                acc[g][n] = __builtin_amdgcn_mfma_f32_16x16x32_bf16(a[g], bb[n], acc[g][n], 0, 0, 0);
    }

    float bias[4][4];
    #pragma unroll
    for (int g = 0; g < 4; ++g)
        #pragma unroll
        for (int r = 0; r < 4; ++r) {
            int m = 128 * g + 16 * wv + lk * 4 + r;
            bias[g][r] = b_itos[m] + b_stos[m];
        }

    uint2* dst = fsp + ((size_t)bs * 8 + wv) * 1024 + l;
    #pragma unroll
    for (int g = 0; g < 4; ++g)
        #pragma unroll
        for (int n = 0; n < 4; ++n) {
            uint2 u;
            u.x = (unsigned)f2bf(acc[g][n][0] + bias[g][0]) | ((unsigned)f2bf(acc[g][n][1] + bias[g][1]) << 16);
            u.y = (unsigned)f2bf(acc[g][n][2] + bias[g][2]) | ((unsigned)f2bf(acc[g][n][3] + bias[g][3]) << 16);
            dst[(g * 4 + n) * 64] = u;
        }
}

// ---------------- phase 2: recurrent, 16 waves, AGPR accumulators -------------
// R7's validated mapping. Wave wv=(vn<<3)|vh: all 4 gates, nh in [16vh,16vh+16),
// w in [32vn,32vn+32). acc[4][2] lives in AGPRs (inline-asm MFMA) so the arch-
// VGPR live set (~46) fits the 64-reg cap of 1024-thread blocks without spill.
__global__ __launch_bounds__(1024) void rowlstm_ag(
    const u16* __restrict__ wsp, const uint2* __restrict__ fsp,
    const float* __restrict__ h0, const float* __restrict__ c0,
    float* __restrict__ out) {
    const int b = blockIdx.x;
    const int t = threadIdx.x, l = t & 63, lr = l & 15, lk = l >> 4;
    const int wv = t >> 6, vh = wv & 7, vn = wv >> 3;
    __shared__ u16 Ht[2 * 8448];   // two buffers: [66][128] u16 each

    // zero the 4 halo rows (wh=0,65 in both buffers)
    if (t < 512) {
        int i = t & 127, z = t >> 7;
        Ht[(z >> 1) * 8448 + ((z & 1) ? 65 : 0) * 128 + i] = 0;
    }
    // h0 into buffer 0 (1024 thr x 8 elems = 8192)
    #pragma unroll
    for (int j = 0; j < 8; ++j) {
        int e = t * 8 + j, nh = e >> 6, w = e & 63, wh = w + 1;
        Ht[wh * 128 + (nh ^ ((wh & 7) << 3))] = f2bf(h0[e]);
    }

    // 8 outputs per lane: nh = 16vh + lk*4 + r, w = 32vn + nn*16 + lr
    float c_r[8];
    #pragma unroll
    for (int nn = 0; nn < 2; ++nn)
        #pragma unroll
        for (int r = 0; r < 4; ++r)
            c_r[nn * 4 + r] = c0[(16 * vh + lk * 4 + r) * 64 + 32 * vn + nn * 16 + lr];

    float* outb = out + ((size_t)b * NHH + 16 * vh + lk * 4) * (NS * NW) + 32 * vn + lr;

    const u16* wbase = wsp + vh * 24576;                      // 4g*12kt*64l*8
    const uint2* fsb = fsp + ((size_t)b * 512 + vh) * 1024 + l;

    __syncthreads();

    unsigned cur = 0;
    for (int s = 0; s < NS; ++s) {
        // fs (bias folded in) -> AGPR accumulator init
        f32x4 acc[4][2];
        {
            uint2 fsv[8];
            #pragma unroll
            for (int g = 0; g < 4; ++g)
                #pragma unroll
                for (int nn = 0; nn < 2; ++nn)
                    fsv[g * 2 + nn] = fsb[(size_t)s * 8192 + (g * 4 + 2 * vn + nn) * 64];
            #pragma unroll
            for (int g = 0; g < 4; ++g)
                #pragma unroll
                for (int nn = 0; nn < 2; ++nn)
                    #pragma unroll
                    for (int r = 0; r < 4; ++r)
                        acc[g][nn][r] = bfreg(fsv[g * 2 + nn], r);
        }
        ACC_PAD1(acc);   // accvgpr_write -> mfma srcC hazard (dep-ordered)

        #pragma unroll
        for (int kt = 0; kt < 12; ++kt) {
            const int d = kt >> 2, kc = kt & 3;
            const int cu = kc * 32 + lk * 8;
            short8 bb[2];
            #pragma unroll
            for (int nn = 0; nn < 2; ++nn) {
                const int wh = (2 * vn + nn) * 16 + lr + d;   // h index = wh-1 = w+d-1
                bb[nn] = *(const short8*)&Ht[cur + wh * 128 + (cu ^ ((wh & 7) << 3))];
            }
            #pragma unroll
            for (int g = 0; g < 4; ++g) {
                short8 a = *(const short8*)(wbase + ((g * 12 + kt) * 64 + l) * 8);
                mfma_a(acc[g][0], a, bb[0]);
                mfma_a(acc[g][1], a, bb[1]);
            }
        }
        ACC_PAD2(acc);   // mfma write -> accvgpr_read hazard (dep-ordered)

        // in-wave gating epilogue; h_new = c_OLD * sigmoid(o)
        const unsigned nxt = cur ^ 8448;
        #pragma unroll
        for (int nn = 0; nn < 2; ++nn) {
            u16 hb[4];
            #pragma unroll
            for (int r = 0; r < 4; ++r) {
                const float si = fsig(acc[0][nn][r]);
                const float tg = ftanh(acc[1][nn][r]);
                const float sf = fsig(acc[2][nn][r]);
                const float so = fsig(acc[3][nn][r]);
                const float cold = c_r[nn * 4 + r];
                c_r[nn * 4 + r] = sf * cold + si * tg;
                const float hn = cold * so;
                outb[(size_t)r * (NS * NW) + s * NW + nn * 16] = hn;
                hb[r] = f2bf(hn);
            }
            uint2 hw;
            hw.x = (unsigned)hb[0] | ((unsigned)hb[1] << 16);
            hw.y = (unsigned)hb[2] | ((unsigned)hb[3] << 16);
            const int nh0 = 16 * vh + lk * 4;
            const int wh = 32 * vn + nn * 16 + lr + 1;
            *(uint2*)&Ht[nxt + wh * 128 + (nh0 ^ ((wh & 7) << 3))] = hw;
        }

        // single barrier per step: drain LDS only, vmem stays in flight
        asm volatile("s_waitcnt lgkmcnt(0)" ::: "memory");
        __builtin_amdgcn_s_barrier();
        asm volatile("" ::: "memory");
        cur = nxt;
    }
}

// ---------------- fallback (validated round-1 fp32 kernel) --------------------
__global__ __launch_bounds__(512, 2) void rowlstm_f32(
    const float* __restrict__ image, const float* __restrict__ w_itos,
    const float* __restrict__ b_itos, const float* __restrict__ w_stos,
    const float* __restrict__ b_stos, const float* __restrict__ h0,
    const float* __restrict__ c0, float* __restrict__ out) {
    const int b = blockIdx.x, t = threadIdx.x, wq = t & 3, nh = t >> 2, w0 = wq * 16;
    __shared__ float h_lds[NHH][NW + 2];
    #pragma unroll
    for (int j = 0; j < 16; ++j) h_lds[nh][1 + w0 + j] = h0[nh * NW + w0 + j];
    if (wq == 0) { h_lds[nh][0] = 0.f; h_lds[nh][NW + 1] = 0.f; }
    float c_r[16];
    #pragma unroll
    for (int j = 0; j < 16; ++j) c_r[j] = c0[nh * NW + w0 + j];
    const float bias[4] = {
        b_itos[0 * NHH + nh] + b_stos[0 * NHH + nh], b_itos[1 * NHH + nh] + b_stos[1 * NHH + nh],
        b_itos[2 * NHH + nh] + b_stos[2 * NHH + nh], b_itos[3 * NHH + nh] + b_stos[3 * NHH + nh]};
    const float* img_b = image + (size_t)b * NC * NS * NW;
    __syncthreads();
    for (int s = 0; s < NS; ++s) {
        float acc[4][16];
        #pragma unroll
        for (int g = 0; g < 4; ++g)
            #pragma unroll
            for (int j = 0; j < 16; ++j) acc[g][j] = bias[g];
        #pragma unroll 2
        for (int ci = 0; ci < NC; ++ci) {
            float imp[16], imc[16];
            const float* iprow = img_b + ((size_t)ci * NS + s) * NW + w0;
            #pragma unroll
            for (int qq = 0; qq < 4; ++qq) {
                float4 vv = *(const float4*)(iprow + 4 * qq);
                imc[4*qq] = vv.x; imc[4*qq+1] = vv.y; imc[4*qq+2] = vv.z; imc[4*qq+3] = vv.w;
            }
            if (s > 0) {
                #pragma unroll
                for (int qq = 0; qq < 4; ++qq) {
                    float4 vv = *(const float4*)(iprow - NW + 4 * qq);
                    imp[4*qq] = vv.x; imp[4*qq+1] = vv.y; imp[4*qq+2] = vv.z; imp[4*qq+3] = vv.w;
                }
            } else {
                #pragma unroll
                for (int j = 0; j < 16; ++j) imp[j] = 0.f;
            }
            float hv[18];
            #pragma unroll
            for (int j = 0; j < 18; ++j) hv[j] = h_lds[ci][w0 + j];
            const float* wip2 = w_itos + ((size_t)nh * NC + ci) * 3;
            const float* wsp2 = w_stos + ((size_t)nh * NHH + ci) * 3;
            #pragma unroll
            for (int g = 0; g < 4; ++g) {
                const float wi0 = wip2[(size_t)g * GSTR + 0], wi1 = wip2[(size_t)g * GSTR + 1];
                const float ws0 = wsp2[(size_t)g * GSTR + 0], ws1 = wsp2[(size_t)g * GSTR + 1],
                            ws2 = wsp2[(size_t)g * GSTR + 2];
                #pragma unroll
                for (int j = 0; j < 16; ++j)
                    acc[g][j] += wi0 * imp[j] + wi1 * imc[j] + ws0 * hv[j] + ws1 * hv[j+1] + ws2 * hv[j+2];
            }
        }
        float hn[16];
        #pragma unroll
        for (int j = 0; j < 16; ++j) {
            const float si = 1.f / (1.f + __expf(-acc[0][j]));
            const float tg = tanhf(acc[1][j]);
            const float sf = 1.f / (1.f + __expf(-acc[2][j]));
            const float so = 1.f / (1.f + __expf(-acc[3][j]));
            const float cold = c_r[j];
            c_r[j] = sf * cold + si * tg;
            hn[j] = cold * so;
        }
        __syncthreads();
        #pragma unroll
        for (int j = 0; j < 16; ++j) h_lds[nh][1 + w0 + j] = hn[j];
        float* opp = out + (((size_t)b * NHH + nh) * NS + s) * NW + w0;
        #pragma unroll
        for (int qq = 0; qq < 4; ++qq)
            *(float4*)(opp + 4 * qq) = make_float4(hn[4*qq], hn[4*qq+1], hn[4*qq+2], hn[4*qq+3]);
        __syncthreads();
    }
}

extern "C" void kernel_launch(void* const* d_in, const int* in_sizes, int n_in,
                              void* d_out, int out_size, void* d_ws, size_t ws_size,
                              hipStream_t stream) {
    const float* image  = (const float*)d_in[0];
    const float* w_itos = (const float*)d_in[1];
    const float* b_itos = (const float*)d_in[2];
    const float* w_stos = (const float*)d_in[3];
    const float* b_stos = (const float*)d_in[4];
    const float* h0     = (const float*)d_in[5];
    const float* c0     = (const float*)d_in[6];
    float* out = (float*)d_out;

    if (ws_size >= WS_NEEDED) {
        u16*   wip = (u16*)((char*)d_ws + WI_OFF);
        u16*   wsp = (u16*)((char*)d_ws + WS_OFF);
        uint2* fsp = (uint2*)((char*)d_ws + FS_OFF);
        pack_weights<<<1280, 256, 0, stream>>>(w_itos, w_stos, wip, wsp);
        itos_gemm<<<1024, 512, 0, stream>>>(image, wip, b_itos, b_stos, fsp);
        rowlstm_ag<<<NB, 1024, 0, stream>>>(wsp, fsp, h0, c0, out);
    } else {
        rowlstm_f32<<<NB, 512, 0, stream>>>(image, w_itos, b_itos, w_stos, b_stos, h0, c0, out);
    }
}